// Round 11
// baseline (361.650 us; speedup 1.0000x reference)
//
#include <hip/hip_runtime.h>
#include <math.h>

#define PIX 36864          // 192*192
#define IMW 192
#define NWIN 4465          // 47*95
#define NWIN_W 95
#define NTASK (NWIN * 6)

typedef short bf16x8 __attribute__((ext_vector_type(8)));
typedef short bf16x4 __attribute__((ext_vector_type(4)));
typedef float floatx4 __attribute__((ext_vector_type(4)));

#if defined(__has_builtin)
#  if __has_builtin(__builtin_amdgcn_rcpf)
#    define RCP(x) __builtin_amdgcn_rcpf(x)
#  endif
#endif
#ifndef RCP
#  define RCP(x) (1.0f / (x))
#endif

__device__ __forceinline__ unsigned short f2bf(float f) {
    union { float f; unsigned u; } v; v.f = f;
    unsigned r = v.u + 0x7fff + ((v.u >> 16) & 1);   // RNE
    return (unsigned short)(r >> 16);
}
__device__ __forceinline__ float bf2f(unsigned short b) {
    union { unsigned u; float f; } v; v.u = ((unsigned)b) << 16;
    return v.f;
}
// round to bf16 (result in high 16 bits)
__device__ __forceinline__ unsigned bfround(float f) {
    union { float f; unsigned u; } v; v.f = f;
    return v.u + 0x7fff + ((v.u >> 16) & 1);
}
// pack two floats as bf16 pair (lo in bits 0-15, hi in bits 16-31) via one v_perm
__device__ __forceinline__ unsigned pk_bf(float lo, float hi) {
    return __builtin_amdgcn_perm(bfround(hi), bfround(lo), 0x07060302u);
}

// ======================= weights->bf16 + ssum zero + pack x : ONE dispatch =======================
__device__ __forceinline__ void emit3(
    const float* __restrict__ wr, const float* __restrict__ wi,
    unsigned short* __restrict__ outr, unsigned short* __restrict__ outi,
    unsigned short* __restrict__ outni, int e)
{
    outr[e] = f2bf(wr[e]);
    unsigned short b = f2bf(wi[e]);
    outi[e]  = b;
    outni[e] = b ^ 0x8000;
}

__global__ __launch_bounds__(256) void prep_kernel(
    const float* __restrict__ qwr, const float* __restrict__ qwi,
    const float* __restrict__ pwr, const float* __restrict__ pwi,
    const float* __restrict__ w2r, const float* __restrict__ w2i,
    const float* __restrict__ xr,  const float* __restrict__ xi,
    unsigned short* __restrict__ wq, unsigned short* __restrict__ wp,
    unsigned short* __restrict__ w2, float* __restrict__ ssum,
    unsigned short* __restrict__ dr, unsigned short* __restrict__ di)
{
    int blk = blockIdx.x;
    if (blk < 108)      { emit3(qwr, qwi, wq, wq + 27648, wq + 55296, blk * 256 + threadIdx.x); return; }
    if (blk < 144)      { emit3(pwr, pwi, wp, wp + 9216,  wp + 18432, (blk - 108) * 256 + threadIdx.x); return; }
    if (blk < 288)      { emit3(w2r, w2i, w2, w2 + 36864, w2 + 73728, (blk - 144) * 256 + threadIdx.x); return; }
    if (blk == 288)     { for (int j = threadIdx.x; j < 768; j += 256) ssum[j] = 0.f; return; }
    // pack x: blocks 289..2016
    int e  = blk - 289;                 // 0..1727
    int kb = e / 144;
    int n  = (e % 144) * 256 + threadIdx.x;
    float fr[8], fi[8];
#pragma unroll
    for (int j = 0; j < 8; ++j) {
        fr[j] = xr[(size_t)(kb * 8 + j) * PIX + n];
        fi[j] = xi[(size_t)(kb * 8 + j) * PIX + n];
    }
    unsigned vr[4], vi[4];
#pragma unroll
    for (int j = 0; j < 4; ++j) {
        vr[j] = pk_bf(fr[j * 2], fr[j * 2 + 1]);
        vi[j] = pk_bf(fi[j * 2], fi[j * 2 + 1]);
    }
    *(uint4*)&dr[((size_t)kb * PIX + n) * 8] = *(uint4*)vr;
    *(uint4*)&di[((size_t)kb * PIX + n) * 8] = *(uint4*)vi;
}

// ======================= complex GEMM via MFMA =======================
// STORE: 2 = qkvb pixel-major slot (V plane interleaved) | 3 = bf16 planar
template<int K, int MT, int STORE>
__global__ __launch_bounds__(256, 2) void cgemm_mfma_kernel(
    const unsigned short* __restrict__ Wr, const unsigned short* __restrict__ Wi,
    const unsigned short* __restrict__ Wni,
    const unsigned short* __restrict__ Xr, const unsigned short* __restrict__ Xi,
    unsigned short* __restrict__ Pr, unsigned short* __restrict__ Pi, int N)
{
    const int lane = threadIdx.x & 63;
    const int wave = threadIdx.x >> 6;
    const int g = lane >> 4;
    const int r = lane & 15;
    const int m0 = (blockIdx.x % MT) * 32;
    const int n0 = (blockIdx.x / MT) * 256 + wave * 64;

    floatx4 accR[2][4], accI[2][4];
#pragma unroll
    for (int t = 0; t < 2; ++t)
#pragma unroll
        for (int j = 0; j < 4; ++j) {
            accR[t][j] = (floatx4){0.f, 0.f, 0.f, 0.f};
            accI[t][j] = (floatx4){0.f, 0.f, 0.f, 0.f};
        }

    for (int kc = 0; kc < K; kc += 32) {
        bf16x8 awr[2], awi[2], awni[2];
#pragma unroll
        for (int t = 0; t < 2; ++t) {
            size_t wb = (size_t)(m0 + t * 16 + r) * K + kc + g * 8;
            awr[t]  = *(const bf16x8*)&Wr[wb];
            awi[t]  = *(const bf16x8*)&Wi[wb];
            awni[t] = *(const bf16x8*)&Wni[wb];
        }
        bf16x8 bxr[4], bxi[4];
        const size_t krow = (size_t)((kc >> 3) + g);
#pragma unroll
        for (int j = 0; j < 4; ++j) {
            size_t off = (krow * N + n0 + j * 16 + r) * 8;
            bxr[j] = *(const bf16x8*)&Xr[off];
            bxi[j] = *(const bf16x8*)&Xi[off];
        }
#pragma unroll
        for (int t = 0; t < 2; ++t)
#pragma unroll
            for (int j = 0; j < 4; ++j) {
                accR[t][j] = __builtin_amdgcn_mfma_f32_16x16x32_bf16(awr[t],  bxr[j], accR[t][j], 0, 0, 0);
                accR[t][j] = __builtin_amdgcn_mfma_f32_16x16x32_bf16(awni[t], bxi[j], accR[t][j], 0, 0, 0);
                accI[t][j] = __builtin_amdgcn_mfma_f32_16x16x32_bf16(awr[t],  bxi[j], accI[t][j], 0, 0, 0);
                accI[t][j] = __builtin_amdgcn_mfma_f32_16x16x32_bf16(awi[t],  bxr[j], accI[t][j], 0, 0, 0);
            }
    }

    if (STORE == 3) {
#pragma unroll
        for (int t = 0; t < 2; ++t)
#pragma unroll
            for (int j = 0; j < 4; ++j) {
                int col = n0 + j * 16 + r;
#pragma unroll
                for (int reg = 0; reg < 4; ++reg) {
                    int row = m0 + t * 16 + g * 4 + reg;
                    Pr[(size_t)row * N + col] = f2bf(accR[t][j][reg]);
                    Pi[(size_t)row * N + col] = f2bf(accI[t][j][reg]);
                }
            }
    } else {
#pragma unroll
        for (int t = 0; t < 2; ++t) {
            int ch0 = m0 + t * 16;
            int which = ch0 / 96;
            int hh = (ch0 % 96) / 16;
#pragma unroll
            for (int j = 0; j < 4; ++j) {
                int col = n0 + j * 16 + r;
                size_t sb = (((size_t)col * 3 + which) * 6 + hh) * 32;
                if (which == 2) {
                    // V plane: interleaved (re,im) per d -> one 16B store
                    unsigned vv[4];
#pragma unroll
                    for (int reg = 0; reg < 4; ++reg)
                        vv[reg] = pk_bf(accR[t][j][reg], accI[t][j][reg]);
                    *(uint4*)&Pr[sb + g * 8] = *(uint4*)vv;
                } else {
                    uint2 pr, pi;
                    pr.x = pk_bf(accR[t][j][0], accR[t][j][1]);
                    pr.y = pk_bf(accR[t][j][2], accR[t][j][3]);
                    pi.x = pk_bf(accI[t][j][0], accI[t][j][1]);
                    pi.y = pk_bf(accI[t][j][2], accI[t][j][3]);
                    *(uint2*)&Pr[sb + g * 4]      = pr;
                    *(uint2*)&Pr[sb + 16 + g * 4] = pi;
                }
            }
        }
    }
}

// ======================= MFMA attention (wave-private LDS, no barriers) =======================
__global__ __launch_bounds__(256) void attn_mfma_kernel(
    const unsigned short* __restrict__ qkvb,
    const float* __restrict__ rel,
    unsigned short* __restrict__ wout)
{
    __shared__ unsigned aLDS[4][32 * 36];
    __shared__ unsigned vLDS[4][32 * 17];

    const int wv   = threadIdx.x >> 6;
    const int lane = threadIdx.x & 63;
    const int lr   = lane & 15;
    const int g    = lane >> 4;

    int t = blockIdx.x * 4 + wv;
    if (t >= NTASK) t = NTASK - 1;
    const int w = t / 6, h = t % 6;
    const int nh = w / NWIN_W, nw = w % NWIN_W;
    const int r0 = nh * 4, c0 = nw * 2;
    const int slot = ((nh & 1) << 1) | (nw & 1);

    unsigned* AL = aLDS[wv];
    unsigned* VL = vLDS[wv];

    auto slotq = [&](int p, int which) -> size_t {
        int gpix = (r0 + (p >> 2)) * IMW + c0 + (p & 3);
        return ((size_t)gpix * 18 + which * 6 + h) * 32;
    };

    // ---- stage V into LDS: direct dword copies (V slot is (re,im)-interleaved) ----
    {
        int m = lane & 31;
        int half = lane >> 5;
        size_t sv = slotq(m, 2);
        uint4 u0 = *(const uint4*)&qkvb[sv + half * 16];
        uint4 u1 = *(const uint4*)&qkvb[sv + half * 16 + 8];
        unsigned* dst = &VL[m * 17 + half * 8];
        dst[0] = u0.x; dst[1] = u0.y; dst[2] = u0.z; dst[3] = u0.w;
        dst[4] = u1.x; dst[5] = u1.y; dst[6] = u1.z; dst[7] = u1.w;
    }
    __asm__ volatile("" ::: "memory");

    // ---- Q/K fragments: half-select folded into address, conj via xor ----
    const int hoff = (g >> 1) * 16;
    const int loff = (g & 1) * 8;
    const unsigned sm = (g >= 2) ? 0x80008000u : 0u;
    bf16x8 Are[2], Aim[2], Bre[2], Bim[2];
#pragma unroll
    for (int tt = 0; tt < 2; ++tt) {
        size_t sq = slotq(tt * 16 + lr, 0);
        size_t sk = slotq(tt * 16 + lr, 1);
        Are[tt] = *(const bf16x8*)&qkvb[sq + hoff + loff];
        Aim[tt] = *(const bf16x8*)&qkvb[sq + (16 - hoff) + loff];
        Bre[tt] = *(const bf16x8*)&qkvb[sk + hoff + loff];
        bf16x8 tmp = Bre[tt];
        unsigned* u = (unsigned*)&tmp;
        u[0] ^= sm; u[1] ^= sm; u[2] ^= sm; u[3] ^= sm;
        Bim[tt] = tmp;
    }

    const floatx4 z4 = (floatx4){0.f, 0.f, 0.f, 0.f};
    floatx4 Sre[2][2], Sim[2][2];
#pragma unroll
    for (int tn = 0; tn < 2; ++tn)
#pragma unroll
        for (int tm = 0; tm < 2; ++tm) {
            Sre[tn][tm] = __builtin_amdgcn_mfma_f32_16x16x32_bf16(Are[tn], Bre[tm], z4, 0, 0, 0);
            Sim[tn][tm] = __builtin_amdgcn_mfma_f32_16x16x32_bf16(Aim[tn], Bim[tm], z4, 0, 0, 0);
        }

    // ---- scale + bias, write RAW logits transposed into LDS ----
    const float* relh = rel + h * 105;
#pragma unroll
    for (int tn = 0; tn < 2; ++tn)
#pragma unroll
        for (int tm = 0; tm < 2; ++tm) {
            int m = tm * 16 + lr;
            int ym = m >> 2, xm = m & 3;
            int yn = tn * 4 + g;
            int bidx = (yn - ym + 7) * 7 + (3 - xm);
#pragma unroll
            for (int reg = 0; reg < 4; ++reg) {
                float re = Sre[tn][tm][reg] * 0.25f + relh[bidx + reg];
                float im = Sim[tn][tm][reg] * 0.25f;
                int n = tn * 16 + g * 4 + reg;
                AL[n * 36 + m] = pk_bf(re, im);
            }
        }
    __asm__ volatile("" ::: "memory");

    // ---- row-owner magnitude softmax: 2 lanes per row, 1 shuffle ----
    {
        const int row = lane & 31;
        const int half = lane >> 5;
        unsigned* rp = &AL[row * 36 + half * 16];
        unsigned pk[16];
        *(uint4*)&pk[0]  = *(const uint4*)&rp[0];
        *(uint4*)&pk[4]  = *(const uint4*)&rp[4];
        *(uint4*)&pk[8]  = *(const uint4*)&rp[8];
        *(uint4*)&pk[12] = *(const uint4*)&rp[12];
        float re[16], im[16], mg[16];
#pragma unroll
        for (int j = 0; j < 16; ++j) {
            union { unsigned u; float f; } a, b;
            a.u = pk[j] << 16;
            b.u = pk[j] & 0xffff0000u;
            re[j] = a.f; im[j] = b.f;
            mg[j] = sqrtf(a.f * a.f + b.f * b.f);
        }
        float mx = mg[0];
#pragma unroll
        for (int j = 1; j < 16; ++j) mx = fmaxf(mx, mg[j]);
        mx = fmaxf(mx, __shfl_xor(mx, 32, 64));
        float es[16], ss = 0.f;
#pragma unroll
        for (int j = 0; j < 16; ++j) { es[j] = __expf(mg[j] - mx); ss += es[j]; }
        ss += __shfl_xor(ss, 32, 64);
        float inv = RCP(ss);
#pragma unroll
        for (int j = 0; j < 16; ++j) {
            float f = es[j] * inv * RCP(mg[j] + 1e-8f);
            pk[j] = pk_bf(re[j] * f, im[j] * f);
        }
        *(uint4*)&rp[0]  = *(uint4*)&pk[0];
        *(uint4*)&rp[4]  = *(uint4*)&pk[4];
        *(uint4*)&rp[8]  = *(uint4*)&pk[8];
        *(uint4*)&rp[12] = *(uint4*)&pk[12];
    }
    __asm__ volatile("" ::: "memory");

    // ---- P = attn · V : 8 MFMAs ----
    floatx4 Pre[2] = {z4, z4}, Pim[2] = {z4, z4};
#pragma unroll
    for (int kc = 0; kc < 2; ++kc) {
        bf16x8 Bpr, Bpi;
        unsigned* bpr = (unsigned*)&Bpr;
        unsigned* bpi = (unsigned*)&Bpi;
#pragma unroll
        for (int p = 0; p < 4; ++p) {
            unsigned pv = VL[(kc * 16 + g * 4 + p) * 17 + lr];
            bpr[p] = pv ^ 0x80000000u;
            bpi[p] = (pv >> 16) | (pv << 16);
        }
#pragma unroll
        for (int tn = 0; tn < 2; ++tn) {
            bf16x8 Af = *(bf16x8*)&AL[(tn * 16 + lr) * 36 + kc * 16 + g * 4];
            Pre[tn] = __builtin_amdgcn_mfma_f32_16x16x32_bf16(Af, Bpr, Pre[tn], 0, 0, 0);
            Pim[tn] = __builtin_amdgcn_mfma_f32_16x16x32_bf16(Af, Bpi, Pim[tn], 0, 0, 0);
        }
    }

    // ---- epilogue: wout[gpix][slot][ch][re,im] ----
#pragma unroll
    for (int tn = 0; tn < 2; ++tn)
#pragma unroll
        for (int reg = 0; reg < 4; ++reg) {
            int n = tn * 16 + g * 4 + reg;
            int gpix = (r0 + (n >> 2)) * IMW + c0 + (n & 3);
            int ch = h * 16 + lr;
            *(unsigned*)&wout[(((size_t)gpix * 4 + slot) * 96 + ch) * 2] =
                pk_bf(Pre[tn][reg], Pim[tn][reg]);
        }
}

// ======================= fold (pixel-major slots) + count-div + pack for proj =======================
__global__ __launch_bounds__(256) void fold_pack_kernel(
    const unsigned short* __restrict__ wout,
    unsigned short* __restrict__ dr, unsigned short* __restrict__ di)
{
    int e = blockIdx.x * 256 + threadIdx.x;   // PIX*12
    int gpix = e / 12;
    int kb   = e % 12;
    int r = gpix / IMW, c = gpix % IMW;
    int nh0 = (r >= 7) ? ((r - 4) >> 2) : 0;
    int nh1 = min(46, r >> 2);
    int nw0 = (c >= 3) ? ((c - 2) >> 1) : 0;
    int nw1 = min(94, c >> 1);

    float accr[8] = {0,0,0,0,0,0,0,0}, acci[8] = {0,0,0,0,0,0,0,0};
    int cnt = 0;
    for (int nh = nh0; nh <= nh1; ++nh)
        for (int nw = nw0; nw <= nw1; ++nw) {
            int slot = ((nh & 1) << 1) | (nw & 1);
            const unsigned short* src = &wout[(((size_t)gpix * 4 + slot) * 96 + kb * 8) * 2];
            bf16x8 a = *(const bf16x8*)&src[0];
            bf16x8 b = *(const bf16x8*)&src[8];
#pragma unroll
            for (int j = 0; j < 4; ++j) {
                accr[j]     += bf2f((unsigned short)a[j*2]);
                acci[j]     += bf2f((unsigned short)a[j*2+1]);
                accr[4 + j] += bf2f((unsigned short)b[j*2]);
                acci[4 + j] += bf2f((unsigned short)b[j*2+1]);
            }
            ++cnt;
        }
    float invc = 1.0f / ((float)cnt + 1e-8f);
    unsigned pr[4], pi[4];
#pragma unroll
    for (int j = 0; j < 4; ++j) {
        pr[j] = pk_bf(accr[j * 2] * invc, accr[j * 2 + 1] * invc);
        pi[j] = pk_bf(acci[j * 2] * invc, acci[j * 2 + 1] * invc);
    }
    *(uint4*)&dr[((size_t)kb * PIX + gpix) * 8] = *(uint4*)pr;
    *(uint4*)&di[((size_t)kb * PIX + gpix) * 8] = *(uint4*)pi;
}

// ======================= 32-value block reduce -> atomics =======================
__device__ __forceinline__ void reduce32_commit(
    float* st, int kb, float* __restrict__ ssum)
{
#pragma unroll
    for (int v = 0; v < 32; ++v)
#pragma unroll
        for (int msk = 1; msk < 64; msk <<= 1)
            st[v] += __shfl_xor(st[v], msk, 64);
    __shared__ float red[4][32];
    const int wv = threadIdx.x >> 6;
    if ((threadIdx.x & 63) == 0)
#pragma unroll
        for (int v = 0; v < 32; ++v) red[wv][v] = st[v];
    __syncthreads();
    if (threadIdx.x < 32) {
        float s = red[0][threadIdx.x] + red[1][threadIdx.x] +
                  red[2][threadIdx.x] + red[3][threadIdx.x];
        int ch = kb * 8 + (threadIdx.x >> 2);
        int stat = threadIdx.x & 3;
        int base = (stat < 2) ? ch : 96 + ch;
        atomicAdd(&ssum[base * 2 + (stat & 1)], s);
    }
}

// ======================= s1 = x + proj(bf16) -> packed bf16 + BN1 stats =======================
__global__ __launch_bounds__(256) void combine_pack_kernel(
    const float* __restrict__ xr, const float* __restrict__ xi,
    const unsigned short* __restrict__ pr, const unsigned short* __restrict__ pi,
    unsigned short* __restrict__ dr, unsigned short* __restrict__ di,
    float* __restrict__ ssum)
{
    const int kb = blockIdx.x / 36;
    const int pb = blockIdx.x % 36;
    const int p0 = pb * 1024;
    float st[32];
#pragma unroll
    for (int v = 0; v < 32; ++v) st[v] = 0.f;

#pragma unroll
    for (int it = 0; it < 4; ++it) {
        int p = p0 + it * 256 + threadIdx.x;
        float a_[8], b_[8];
#pragma unroll
        for (int ch = 0; ch < 8; ++ch) {
            int c = kb * 8 + ch;
            a_[ch] = xr[(size_t)c * PIX + p] + bf2f(pr[(size_t)c * PIX + p]);
            b_[ch] = xi[(size_t)c * PIX + p] + bf2f(pi[(size_t)c * PIX + p]);
            st[ch * 4 + 0] += a_[ch]; st[ch * 4 + 1] += a_[ch] * a_[ch];
            st[ch * 4 + 2] += b_[ch]; st[ch * 4 + 3] += b_[ch] * b_[ch];
        }
        unsigned vr[4], vi[4];
#pragma unroll
        for (int j = 0; j < 4; ++j) {
            vr[j] = pk_bf(a_[j * 2], a_[j * 2 + 1]);
            vi[j] = pk_bf(b_[j * 2], b_[j * 2 + 1]);
        }
        *(uint4*)&dr[((size_t)kb * PIX + p) * 8] = *(uint4*)vr;
        *(uint4*)&di[((size_t)kb * PIX + p) * 8] = *(uint4*)vi;
    }
    reduce32_commit(st, kb, ssum);
}

// ======================= build BN1-folded mlp1 weights + bias =======================
__global__ __launch_bounds__(256) void scale_w_kernel(
    const float* __restrict__ w1r, const float* __restrict__ w1i,
    const float* __restrict__ gr, const float* __restrict__ br,
    const float* __restrict__ gi, const float* __restrict__ bi,
    const float* __restrict__ ssum1,
    unsigned short* __restrict__ W0, unsigned short* __restrict__ W1,
    unsigned short* __restrict__ W2, unsigned short* __restrict__ W3,
    float* __restrict__ biasR, float* __restrict__ biasI)
{
    const float invn = 1.0f / (float)PIX;
    int blk = blockIdx.x;
    if (blk < 576) {
        int e = blk * 256 + threadIdx.x;
        int mat = e / 36864;
        int idx = e % 36864;
        int k = idx % 96;
        float mr = ssum1[k * 2] * invn;
        float a_r = gr[k] * rsqrtf(ssum1[k * 2 + 1] * invn - mr * mr + 1e-5f);
        float mi = ssum1[(96 + k) * 2] * invn;
        float a_i = gi[k] * rsqrtf(ssum1[(96 + k) * 2 + 1] * invn - mi * mi + 1e-5f);
        float wr = w1r[idx], wi = w1i[idx];
        float v = (mat == 0) ? wr * a_r : (mat == 1) ? -wi * a_i
                : (mat == 2) ? wr * a_i : wi * a_r;
        unsigned short* dst = (mat == 0) ? W0 : (mat == 1) ? W1 : (mat == 2) ? W2 : W3;
        dst[idx] = f2bf(v);
    } else {
        int o = (blk - 576) * 256 + threadIdx.x;
        if (o >= 768) return;
        int isI = o >= 384;
        int oo = o % 384;
        float acc = 0.f;
        for (int k = 0; k < 96; ++k) {
            float mr = ssum1[k * 2] * invn;
            float a_r = gr[k] * rsqrtf(ssum1[k * 2 + 1] * invn - mr * mr + 1e-5f);
            float c_r = br[k] - a_r * mr;
            float mi = ssum1[(96 + k) * 2] * invn;
            float a_i = gi[k] * rsqrtf(ssum1[(96 + k) * 2 + 1] * invn - mi * mi + 1e-5f);
            float c_i = bi[k] - a_i * mi;
            float wr = w1r[oo * 96 + k], wi = w1i[oo * 96 + k];
            acc += isI ? (wr * c_i + wi * c_r) : (wr * c_r - wi * c_i);
        }
        (isI ? biasI : biasR)[oo] = acc;
    }
}

// ======================= mlp1 (BN folded) + bias + cgelu -> packed bf16 hidden =======================
__global__ __launch_bounds__(256, 2) void mlp1bn_kernel(
    const unsigned short* __restrict__ W0, const unsigned short* __restrict__ W1,
    const unsigned short* __restrict__ W2, const unsigned short* __restrict__ W3,
    const float* __restrict__ biasR, const float* __restrict__ biasI,
    const unsigned short* __restrict__ Xr, const unsigned short* __restrict__ Xi,
    unsigned short* __restrict__ Pr, unsigned short* __restrict__ Pi, int N)
{
    const int lane = threadIdx.x & 63;
    const int wave = threadIdx.x >> 6;
    const int g = lane >> 4;
    const int r = lane & 15;
    const int m0 = (blockIdx.x % 12) * 32;
    const int n0 = (blockIdx.x / 12) * 256 + wave * 64;
    const int K = 96;

    floatx4 accR[2][4], accI[2][4];
#pragma unroll
    for (int t = 0; t < 2; ++t)
#pragma unroll
        for (int j = 0; j < 4; ++j) {
            accR[t][j] = (floatx4){0.f, 0.f, 0.f, 0.f};
            accI[t][j] = (floatx4){0.f, 0.f, 0.f, 0.f};
        }

    for (int kc = 0; kc < K; kc += 32) {
        bf16x8 a0[2], a1[2], a2[2], a3[2];
#pragma unroll
        for (int t = 0; t < 2; ++t) {
            size_t wb = (size_t)(m0 + t * 16 + r) * K + kc + g * 8;
            a0[t] = *(const bf16x8*)&W0[wb];
            a1[t] = *(const bf16x8*)&W1[wb];
            a2[t] = *(const bf16x8*)&W2[wb];
            a3[t] = *(const bf16x8*)&W3[wb];
        }
        bf16x8 bxr[4], bxi[4];
        const size_t krow = (size_t)((kc >> 3) + g);
#pragma unroll
        for (int j = 0; j < 4; ++j) {
            size_t off = (krow * N + n0 + j * 16 + r) * 8;
            bxr[j] = *(const bf16x8*)&Xr[off];
            bxi[j] = *(const bf16x8*)&Xi[off];
        }
#pragma unroll
        for (int t = 0; t < 2; ++t)
#pragma unroll
            for (int j = 0; j < 4; ++j) {
                accR[t][j] = __builtin_amdgcn_mfma_f32_16x16x32_bf16(a0[t], bxr[j], accR[t][j], 0, 0, 0);
                accR[t][j] = __builtin_amdgcn_mfma_f32_16x16x32_bf16(a1[t], bxi[j], accR[t][j], 0, 0, 0);
                accI[t][j] = __builtin_amdgcn_mfma_f32_16x16x32_bf16(a2[t], bxi[j], accI[t][j], 0, 0, 0);
                accI[t][j] = __builtin_amdgcn_mfma_f32_16x16x32_bf16(a3[t], bxr[j], accI[t][j], 0, 0, 0);
            }
    }

#pragma unroll
    for (int t = 0; t < 2; ++t) {
        float bR[4], bI[4];
#pragma unroll
        for (int reg = 0; reg < 4; ++reg) {
            int row = m0 + t * 16 + g * 4 + reg;
            bR[reg] = biasR[row];
            bI[reg] = biasI[row];
        }
#pragma unroll
        for (int j = 0; j < 4; ++j) {
            int col = n0 + j * 16 + r;
            size_t rowblk = (size_t)((m0 + t * 16 + g * 4) >> 3);
            int sub = (g & 1) * 4;
            float cr[4], ci[4];
#pragma unroll
            for (int reg = 0; reg < 4; ++reg) {
                float a = accR[t][j][reg] + bR[reg];
                float b = accI[t][j][reg] + bI[reg];
                float mag = sqrtf(a * a + b * b);
                float f = (0.5f + 0.5f * erff(mag * 0.70710678118654752f)) * mag * RCP(mag + 1e-8f);
                cr[reg] = a * f;
                ci[reg] = b * f;
            }
            uint2 pr, pi;
            pr.x = pk_bf(cr[0], cr[1]); pr.y = pk_bf(cr[2], cr[3]);
            pi.x = pk_bf(ci[0], ci[1]); pi.y = pk_bf(ci[2], ci[3]);
            *(uint2*)&Pr[(rowblk * N + col) * 8 + sub] = pr;
            *(uint2*)&Pi[(rowblk * N + col) * 8 + sub] = pi;
        }
    }
}

// ======================= s2 = m(bf16) + bn1(s1) -> bf16 planar + BN2 stats =======================
__global__ __launch_bounds__(256) void addbn_kernel(
    const unsigned short* __restrict__ dr, const unsigned short* __restrict__ di,
    const float* __restrict__ ssum1,
    const float* __restrict__ gr, const float* __restrict__ br,
    const float* __restrict__ gi, const float* __restrict__ bi,
    const unsigned short* __restrict__ mr_, const unsigned short* __restrict__ mi_,
    unsigned short* __restrict__ s2r, unsigned short* __restrict__ s2i,
    float* __restrict__ ssum2)
{
    const int kb = blockIdx.x / 36;
    const int pb = blockIdx.x % 36;
    const int p0 = pb * 1024;
    const float invn = 1.0f / (float)PIX;

    float ar[8], cr[8], ai[8], ci[8];
#pragma unroll
    for (int ch = 0; ch < 8; ++ch) {
        int c = kb * 8 + ch;
        float mr = ssum1[c * 2] * invn;
        ar[ch] = gr[c] * rsqrtf(ssum1[c * 2 + 1] * invn - mr * mr + 1e-5f);
        cr[ch] = br[c] - ar[ch] * mr;
        float mi = ssum1[(96 + c) * 2] * invn;
        ai[ch] = gi[c] * rsqrtf(ssum1[(96 + c) * 2 + 1] * invn - mi * mi + 1e-5f);
        ci[ch] = bi[c] - ai[ch] * mi;
    }

    float st[32];
#pragma unroll
    for (int v = 0; v < 32; ++v) st[v] = 0.f;

#pragma unroll
    for (int it = 0; it < 4; ++it) {
        int p = p0 + it * 256 + threadIdx.x;
        bf16x8 s1r = *(const bf16x8*)&dr[((size_t)kb * PIX + p) * 8];
        bf16x8 s1i = *(const bf16x8*)&di[((size_t)kb * PIX + p) * 8];
#pragma unroll
        for (int ch = 0; ch < 8; ++ch) {
            int c = kb * 8 + ch;
            float vr = bf2f(mr_[(size_t)c * PIX + p]) + ar[ch] * bf2f((unsigned short)s1r[ch]) + cr[ch];
            float vi = bf2f(mi_[(size_t)c * PIX + p]) + ai[ch] * bf2f((unsigned short)s1i[ch]) + ci[ch];
            s2r[(size_t)c * PIX + p] = f2bf(vr);
            s2i[(size_t)c * PIX + p] = f2bf(vi);
            st[ch * 4 + 0] += vr; st[ch * 4 + 1] += vr * vr;
            st[ch * 4 + 2] += vi; st[ch * 4 + 3] += vi * vi;
        }
    }
    reduce32_commit(st, kb, ssum2);
}

// ======================= final BN2 apply =======================
__global__ __launch_bounds__(256) void bn_apply_kernel(
    const unsigned short* __restrict__ s2r, const unsigned short* __restrict__ s2i,
    const float* __restrict__ gr, const float* __restrict__ br,
    const float* __restrict__ gi, const float* __restrict__ bi,
    const float* __restrict__ ssum2,
    float* __restrict__ outr, float* __restrict__ outi)
{
    int e = blockIdx.x * 256 + threadIdx.x;
    if (e >= 96 * PIX) return;
    int ch = e / PIX;
    const float invn = 1.0f / (float)PIX;
    float mr = ssum2[ch * 2] * invn;
    float isr = rsqrtf(ssum2[ch * 2 + 1] * invn - mr * mr + 1e-5f);
    float mi = ssum2[(96 + ch) * 2] * invn;
    float isi = rsqrtf(ssum2[(96 + ch) * 2 + 1] * invn - mi * mi + 1e-5f);
    outr[e] = gr[ch] * (bf2f(s2r[e]) - mr) * isr + br[ch];
    outi[e] = gi[ch] * (bf2f(s2i[e]) - mi) * isi + bi[ch];
}

// ======================= launch =======================
extern "C" void kernel_launch(void* const* d_in, const int* in_sizes, int n_in,
                              void* d_out, int out_size, void* d_ws, size_t ws_size,
                              hipStream_t stream)
{
    const float* x_r     = (const float*)d_in[0];
    const float* x_i     = (const float*)d_in[1];
    const float* qkv_wr  = (const float*)d_in[2];
    const float* qkv_wi  = (const float*)d_in[3];
    const float* proj_wr = (const float*)d_in[4];
    const float* proj_wi = (const float*)d_in[5];
    const float* rel     = (const float*)d_in[6];
    const float* mlp1_wr = (const float*)d_in[7];
    const float* mlp1_wi = (const float*)d_in[8];
    const float* mlp2_wr = (const float*)d_in[9];
    const float* mlp2_wi = (const float*)d_in[10];
    const float* n1_gr   = (const float*)d_in[11];
    const float* n1_br   = (const float*)d_in[12];
    const float* n1_gi   = (const float*)d_in[13];
    const float* n1_bi   = (const float*)d_in[14];
    const float* n2_gr   = (const float*)d_in[15];
    const float* n2_br   = (const float*)d_in[16];
    const float* n2_gi   = (const float*)d_in[17];
    const float* n2_bi   = (const float*)d_in[18];

    const size_t P = PIX;
    char* base = (char*)d_ws;

    unsigned short* Dr = (unsigned short*)base;           // packed operand / packed s1
    unsigned short* Di = Dr + 96 * P;
    char* R = (char*)(Di + 96 * P);                       // overlay region
    unsigned short* qkvb = (unsigned short*)R;            // 576*P ushorts
    unsigned short* wout = qkvb + 576 * P;                // PIX*4*96*2 ushorts
    unsigned short* pm_r = (unsigned short*)R;            // proj / m bf16 planar
    unsigned short* pm_i = pm_r + 96 * P;
    unsigned short* hid_r = pm_i + 96 * P;                // packed hidden re (384*P)
    unsigned short* hid_i = hid_r + 384 * P;
    unsigned short* Wb = wout + (size_t)P * 4 * 96 * 2;

    unsigned short* wq = Wb;                    // 3 x 27648
    unsigned short* wp = Wb + 82944;            // 3 x 9216
    unsigned short* w2 = Wb + 110592;           // 3 x 36864
    unsigned short* W1s = Wb + 221184;          // 4 x 36864
    float* biasR = (float*)(Wb + 368640);
    float* biasI = biasR + 384;
    float* ssum1 = biasI + 384;
    float* ssum2 = ssum1 + 384;
    unsigned short* s2r = (unsigned short*)(ssum2 + 384);
    unsigned short* s2i = s2r + 96 * P;

    float* out_r = (float*)d_out;
    float* out_i = out_r + 96 * P;

    dim3 blk(256);

    // 0. weights -> bf16 + zero ssum + pack x (ONE dispatch)
    prep_kernel<<<dim3(2017), blk, 0, stream>>>(
        qkv_wr, qkv_wi, proj_wr, proj_wi, mlp2_wr, mlp2_wi, x_r, x_i,
        wq, wp, w2, ssum1, Dr, Di);
    // 1. QKV gemm -> qkvb (V plane interleaved)
    cgemm_mfma_kernel<96, 9, 2><<<dim3(9 * 144), blk, 0, stream>>>(
        wq, wq + 27648, wq + 55296, Dr, Di, qkvb, nullptr, PIX);
    // 2. attention -> wout
    attn_mfma_kernel<<<dim3((NTASK + 3) / 4), blk, 0, stream>>>(qkvb, rel, wout);
    // 3. fold + /counts + pack for proj
    fold_pack_kernel<<<dim3(1728), blk, 0, stream>>>(wout, Dr, Di);
    // 4. proj gemm -> bf16 planar pm
    cgemm_mfma_kernel<96, 3, 3><<<dim3(3 * 144), blk, 0, stream>>>(
        wp, wp + 9216, wp + 18432, Dr, Di, pm_r, pm_i, PIX);
    // 5. s1 = x + proj -> packed bf16 + BN1 stats
    combine_pack_kernel<<<dim3(432), blk, 0, stream>>>(x_r, x_i, pm_r, pm_i, Dr, Di, ssum1);
    // 6. build BN1-folded mlp1 weights + bias
    scale_w_kernel<<<dim3(579), blk, 0, stream>>>(
        mlp1_wr, mlp1_wi, n1_gr, n1_br, n1_gi, n1_bi, ssum1,
        W1s, W1s + 36864, W1s + 73728, W1s + 110592, biasR, biasI);
    // 7. mlp1 (BN folded) + bias + cgelu -> packed hidden
    mlp1bn_kernel<<<dim3(12 * 144), blk, 0, stream>>>(
        W1s, W1s + 36864, W1s + 73728, W1s + 110592, biasR, biasI,
        Dr, Di, hid_r, hid_i, PIX);
    // 8. mlp2 gemm -> m (bf16 planar pm)
    cgemm_mfma_kernel<384, 3, 3><<<dim3(3 * 144), blk, 0, stream>>>(
        w2, w2 + 36864, w2 + 73728, hid_r, hid_i, pm_r, pm_i, PIX);
    // 9. s2 = m + bn1(s1) -> bf16 planar + BN2 stats
    addbn_kernel<<<dim3(432), blk, 0, stream>>>(Dr, Di, ssum1,
        n1_gr, n1_br, n1_gi, n1_bi, pm_r, pm_i, s2r, s2i, ssum2);
    // 10. BN2 apply -> out
    bn_apply_kernel<<<dim3(13824), blk, 0, stream>>>(s2r, s2i,
        n2_gr, n2_br, n2_gi, n2_bi, ssum2, out_r, out_i);
}